// Round 1
// baseline (6551.824 us; speedup 1.0000x reference)
//
#include <hip/hip_runtime.h>
#include <stdint.h>

// Problem dims
#define HDIM   1024
#define BDIM   128
#define TSTEPS 128
#define DDIM   256
#define ODIM   1024

// Workspace byte offsets
#define WS_CNT   0
#define WS_HBUF  4096                                  // ushort [2][128][1024]
#define WS_HFIN  (WS_HBUF + 2*BDIM*HDIM*2)             // float  [128][1024]
#define WS_PBUF  (WS_HFIN + BDIM*HDIM*4)               // float  [128][1024]
#define WS_WHHI  (WS_PBUF + BDIM*ODIM*4)               // ushort [4096][1024]
#define WS_WHLO  (WS_WHHI + 4*HDIM*HDIM*2)             // ushort [4096][1024]
#define WS_WXHI  (WS_WHLO + 4*HDIM*HDIM*2)             // ushort [4096][256]
#define WS_XT    (WS_WXHI + 4*HDIM*DDIM*2)             // ushort [128][128][256]

// LDS layout (rows padded: 1288*2B=2576B=644 dw, 1032*2B=2064B=516 dw; both ≡4 mod 32 → conflict-free b128)
#define SMEM_WHI_ROW 1288   // 1024 Wh_hi + 256 Wx_hi + 8 pad
#define SMEM_WLO_ROW 1032   // 1024 Wh_lo + 8 pad
#define SMEM_BYTES   (32*SMEM_WHI_ROW*2 + 32*SMEM_WLO_ROW*2 + 64*33*4)  // 156,928 B

typedef __attribute__((ext_vector_type(8))) short frag8;
typedef __attribute__((ext_vector_type(4))) float f32x4;

__device__ __forceinline__ unsigned short f2bf(float f) {
  union { float f; unsigned u; } v; v.f = f;
  unsigned r = v.u + 0x7fffu + ((v.u >> 16) & 1u);   // RNE
  return (unsigned short)(r >> 16);
}
__device__ __forceinline__ float bf2f(unsigned short h) {
  union { unsigned u; float f; } v; v.u = ((unsigned)h) << 16;
  return v.f;
}
__device__ __forceinline__ float sigm(float x) { return 1.f / (1.f + __expf(-x)); }
__device__ __forceinline__ float tanh_f(float x) {
  x = fminf(fmaxf(x, -20.f), 20.f);
  float e = __expf(2.f * x);
  return (e - 1.f) / (e + 1.f);
}

// ---------------- prep: fp32 -> bf16 (hi/lo) reformat + x transpose ----------------
__global__ void prep_kernel(const float* __restrict__ Wh, const float* __restrict__ Wx,
                            const float* __restrict__ x, unsigned char* __restrict__ ws)
{
  unsigned short* whhi = (unsigned short*)(ws + WS_WHHI);
  unsigned short* whlo = (unsigned short*)(ws + WS_WHLO);
  unsigned short* wxhi = (unsigned short*)(ws + WS_WXHI);
  unsigned short* xt   = (unsigned short*)(ws + WS_XT);
  const int NWH = 4*HDIM*HDIM/4;       // 1,048,576 float4 items
  const int NWX = 4*HDIM*DDIM/4;       //   262,144
  const int NX  = BDIM*TSTEPS*DDIM/4;  // 1,048,576
  int stride = gridDim.x * blockDim.x;
  for (int i = blockIdx.x*blockDim.x + threadIdx.x; i < NWH+NWX+NX; i += stride) {
    if (i < NWH) {
      float4 w = ((const float4*)Wh)[i];
      ushort4 hi, lo;
      hi.x = f2bf(w.x); lo.x = f2bf(w.x - bf2f(hi.x));
      hi.y = f2bf(w.y); lo.y = f2bf(w.y - bf2f(hi.y));
      hi.z = f2bf(w.z); lo.z = f2bf(w.z - bf2f(hi.z));
      hi.w = f2bf(w.w); lo.w = f2bf(w.w - bf2f(hi.w));
      ((ushort4*)whhi)[i] = hi;
      ((ushort4*)whlo)[i] = lo;
    } else if (i < NWH + NWX) {
      int j = i - NWH;
      float4 w = ((const float4*)Wx)[j];
      ushort4 hi;
      hi.x = f2bf(w.x); hi.y = f2bf(w.y); hi.z = f2bf(w.z); hi.w = f2bf(w.w);
      ((ushort4*)wxhi)[j] = hi;
    } else {
      int j = i - NWH - NWX;           // x flat [b][t][dv], dv = float4 index
      int dv = j & 63;
      int t  = (j >> 6) & (TSTEPS - 1);
      int b  = j >> 13;
      float4 w = ((const float4*)x)[j];
      ushort4 hv;
      hv.x = f2bf(w.x); hv.y = f2bf(w.y); hv.z = f2bf(w.z); hv.w = f2bf(w.w);
      ((ushort4*)xt)[((size_t)t*BDIM + b)*64 + dv] = hv;   // xT[t][b][d]
    }
  }
}

// ---------------- persistent LSTM kernel (cooperative, 256 blocks x 256 thr) ----------------
// Block (mh = blockIdx&1, nsl = blockIdx>>1): batch rows [mh*64, +64), h-cols [nsl*8, +8)
// -> owns 32 gate rows {g,i,f,o} x 8, weights resident in LDS across all 128 steps.
__global__ void __launch_bounds__(256, 1)
lstm_main(const float* __restrict__ bx, const float* __restrict__ Wp,
          const float* __restrict__ bp, unsigned char* __restrict__ ws,
          float* __restrict__ out)
{
  extern __shared__ unsigned char smem[];
  unsigned short* sWhi = (unsigned short*)smem;                            // [32][1288]
  unsigned short* sWlo = (unsigned short*)(smem + 32*SMEM_WHI_ROW*2);      // [32][1032]
  float*          sG   = (float*)(smem + 32*SMEM_WHI_ROW*2 + 32*SMEM_WLO_ROW*2); // [64][33]

  unsigned*       cnt  = (unsigned*)(ws + WS_CNT);
  unsigned short* hbuf = (unsigned short*)(ws + WS_HBUF);
  float*          hfin = (float*)(ws + WS_HFIN);
  float*          pbuf = (float*)(ws + WS_PBUF);
  const unsigned short* whhi = (const unsigned short*)(ws + WS_WHHI);
  const unsigned short* whlo = (const unsigned short*)(ws + WS_WHLO);
  const unsigned short* wxhi = (const unsigned short*)(ws + WS_WXHI);
  const unsigned short* xt   = (const unsigned short*)(ws + WS_XT);

  const int tid  = threadIdx.x;
  const int lane = tid & 63;
  const int wv   = tid >> 6;      // wave 0..3 -> m-tile
  const int fr   = lane & 15;     // MFMA frag row (m for A, n for B)
  const int fg   = lane >> 4;     // k-group 0..3
  const int mh   = blockIdx.x & 1;
  const int nsl  = blockIdx.x >> 1;
  const int hc0  = nsl << 3;
  const int m0   = mh << 6;

  // ---- stage this block's weight slice into LDS (once) ----
  for (int lr = 0; lr < 32; ++lr) {
    int grow = (lr >> 3) * HDIM + hc0 + (lr & 7);   // gate*H + hcol
    ((ushort4*)(sWhi + lr*SMEM_WHI_ROW))[tid] =
        ((const ushort4*)(whhi + (size_t)grow*HDIM))[tid];
    ((ushort4*)(sWlo + lr*SMEM_WLO_ROW))[tid] =
        ((const ushort4*)(whlo + (size_t)grow*HDIM))[tid];
    if (tid < 64)
      ((ushort4*)(sWhi + lr*SMEM_WHI_ROW + 1024))[tid] =
          ((const ushort4*)(wxhi + (size_t)grow*DDIM))[tid];
  }
  __syncthreads();

  // update-phase mapping: items (uml0,uj) and (uml1,uj); biases invariant over t -> hoist
  const int uj   = tid & 7;
  const int uml0 = tid >> 3;
  const int uml1 = uml0 + 32;
  const float bg = bx[0*HDIM + hc0 + uj];
  const float bi = bx[1*HDIM + hc0 + uj];
  const float bf = bx[2*HDIM + hc0 + uj];
  const float bo = bx[3*HDIM + hc0 + uj];

  float c0 = 0.f, c1 = 0.f;
  const int arow = m0 + wv*16 + fr;   // global batch row for this lane's A-frags

  for (int t = 0; t < TSTEPS; ++t) {
    f32x4 acc0 = {0.f, 0.f, 0.f, 0.f};
    f32x4 acc1 = {0.f, 0.f, 0.f, 0.f};

    // ---- x-path (independent of h_t: runs between prev arrive and this wait) ----
    {
      const unsigned short* xrow = xt + ((size_t)t*BDIM + arow)*DDIM + fg*8;
      #pragma unroll
      for (int kc = 0; kc < 8; ++kc) {
        frag8 a  = *(const frag8*)(xrow + kc*32);
        frag8 b0 = *(const frag8*)(sWhi + fr*SMEM_WHI_ROW      + 1024 + kc*32 + fg*8);
        frag8 b1 = *(const frag8*)(sWhi + (16+fr)*SMEM_WHI_ROW + 1024 + kc*32 + fg*8);
        acc0 = __builtin_amdgcn_mfma_f32_16x16x32_bf16(a, b0, acc0, 0, 0, 0);
        acc1 = __builtin_amdgcn_mfma_f32_16x16x32_bf16(a, b1, acc1, 0, 0, 0);
      }
    }

    // ---- wait: h_t published by all blocks (monotonic counter, agent scope) ----
    if (tid == 0) {
      unsigned tgt = 256u * (unsigned)t;
      while (__hip_atomic_load(cnt, __ATOMIC_RELAXED, __HIP_MEMORY_SCOPE_AGENT) < tgt)
        __builtin_amdgcn_s_sleep(2);
      __threadfence();
    }
    __syncthreads();
    __threadfence();

    // ---- h-path: gates += h_t @ (Wh_hi + Wh_lo)^T ----
    {
      const unsigned short* hrow = hbuf + ((size_t)(t & 1)*BDIM + arow)*HDIM + fg*8;
      #pragma unroll 8
      for (int kc = 0; kc < 32; ++kc) {
        frag8 a   = *(const frag8*)(hrow + kc*32);
        frag8 bh0 = *(const frag8*)(sWhi + fr*SMEM_WHI_ROW      + kc*32 + fg*8);
        frag8 bh1 = *(const frag8*)(sWhi + (16+fr)*SMEM_WHI_ROW + kc*32 + fg*8);
        frag8 bl0 = *(const frag8*)(sWlo + fr*SMEM_WLO_ROW      + kc*32 + fg*8);
        frag8 bl1 = *(const frag8*)(sWlo + (16+fr)*SMEM_WLO_ROW + kc*32 + fg*8);
        acc0 = __builtin_amdgcn_mfma_f32_16x16x32_bf16(a, bh0, acc0, 0, 0, 0);
        acc1 = __builtin_amdgcn_mfma_f32_16x16x32_bf16(a, bh1, acc1, 0, 0, 0);
        acc0 = __builtin_amdgcn_mfma_f32_16x16x32_bf16(a, bl0, acc0, 0, 0, 0);
        acc1 = __builtin_amdgcn_mfma_f32_16x16x32_bf16(a, bl1, acc1, 0, 0, 0);
      }
    }

    // ---- scatter accs to LDS (C/D layout: col=lane&15, row=(lane>>4)*4+reg) ----
    {
      int mb = wv*16 + fg*4;
      #pragma unroll
      for (int r = 0; r < 4; ++r) {
        sG[(mb + r)*33 + fr]      = acc0[r];
        sG[(mb + r)*33 + 16 + fr] = acc1[r];
      }
    }
    __syncthreads();

    // ---- gate nonlinearities + state update (c stays in registers) ----
    {
      float gg0 = sG[uml0*33 + uj]      + bg;
      float gi0 = sG[uml0*33 + 8 + uj]  + bi;
      float gf0 = sG[uml0*33 + 16 + uj] + bf;
      float go0 = sG[uml0*33 + 24 + uj] + bo;
      float gg1 = sG[uml1*33 + uj]      + bg;
      float gi1 = sG[uml1*33 + 8 + uj]  + bi;
      float gf1 = sG[uml1*33 + 16 + uj] + bf;
      float go1 = sG[uml1*33 + 24 + uj] + bo;

      c0 = tanh_f(gg0)*sigm(gi0) + c0*sigm(gf0);
      c1 = tanh_f(gg1)*sigm(gi1) + c1*sigm(gf1);
      float h0 = tanh_f(c0)*sigm(go0);
      float h1 = tanh_f(c1)*sigm(go1);

      unsigned short* hw = hbuf + (size_t)((t + 1) & 1)*BDIM*HDIM;
      hw[(size_t)(m0 + uml0)*HDIM + hc0 + uj] = f2bf(h0);
      hw[(size_t)(m0 + uml1)*HDIM + hc0 + uj] = f2bf(h1);
      if (t == TSTEPS - 1) {
        hfin[(size_t)(m0 + uml0)*HDIM + hc0 + uj] = h0;
        hfin[(size_t)(m0 + uml1)*HDIM + hc0 + uj] = h1;
      }
    }

    // ---- arrive (release) ----
    __threadfence();
    __syncthreads();
    if (tid == 0)
      __hip_atomic_fetch_add(cnt, 1u, __ATOMIC_RELAXED, __HIP_MEMORY_SCOPE_AGENT);
  }

  // ---- wait: all blocks finished all steps (hfin complete) ----
  if (tid == 0) {
    while (__hip_atomic_load(cnt, __ATOMIC_RELAXED, __HIP_MEMORY_SCOPE_AGENT) < 256u*TSTEPS)
      __builtin_amdgcn_s_sleep(2);
    __threadfence();
  }
  __syncthreads();
  __threadfence();

  // ---- projection: p = h_last @ Wp^T + bp (fp32 vector; block covers [m0,+64) x [hc0,+8)) ----
  {
    #pragma unroll
    for (int it = 0; it < 2; ++it) {
      int ml = (it == 0) ? uml0 : uml1;
      int m = m0 + ml, n = hc0 + uj;
      const float4* hr = (const float4*)(hfin + (size_t)m*HDIM);
      const float4* wr = (const float4*)(Wp + (size_t)n*HDIM);
      float s = 0.f;
      #pragma unroll 4
      for (int k = 0; k < HDIM/4; ++k) {
        float4 a = hr[k], b = wr[k];
        s += a.x*b.x + a.y*b.y + a.z*b.z + a.w*b.w;
      }
      pbuf[(size_t)m*ODIM + n] = s + bp[n];
    }
  }

  __threadfence();
  __syncthreads();
  if (tid == 0)
    __hip_atomic_fetch_add(cnt, 1u, __ATOMIC_RELAXED, __HIP_MEMORY_SCOPE_AGENT);

  if (blockIdx.x >= BDIM) return;

  if (tid == 0) {
    while (__hip_atomic_load(cnt, __ATOMIC_RELAXED, __HIP_MEMORY_SCOPE_AGENT) < 256u*(TSTEPS+1))
      __builtin_amdgcn_s_sleep(2);
    __threadfence();
  }
  __syncthreads();
  __threadfence();

  // ---- softmax: one block per batch row ----
  {
    int b = blockIdx.x;
    float4 v = ((const float4*)(pbuf + (size_t)b*ODIM))[tid];
    float mx = fmaxf(fmaxf(v.x, v.y), fmaxf(v.z, v.w));
    #pragma unroll
    for (int off = 32; off > 0; off >>= 1)
      mx = fmaxf(mx, __shfl_xor(mx, off, 64));
    if (lane == 0) sG[wv] = mx;
    __syncthreads();
    mx = fmaxf(fmaxf(sG[0], sG[1]), fmaxf(sG[2], sG[3]));
    float e0 = __expf(v.x - mx), e1 = __expf(v.y - mx),
          e2 = __expf(v.z - mx), e3 = __expf(v.w - mx);
    float s = e0 + e1 + e2 + e3;
    #pragma unroll
    for (int off = 32; off > 0; off >>= 1)
      s += __shfl_xor(s, off, 64);
    if (lane == 0) sG[8 + wv] = s;
    __syncthreads();
    s = sG[8] + sG[9] + sG[10] + sG[11];
    float inv = 1.f / s;
    float4 o; o.x = e0*inv; o.y = e1*inv; o.z = e2*inv; o.w = e3*inv;
    ((float4*)(out + (size_t)b*ODIM))[tid] = o;
  }
}

// ---------------- host launch ----------------
extern "C" void kernel_launch(void* const* d_in, const int* in_sizes, int n_in,
                              void* d_out, int out_size, void* d_ws, size_t ws_size,
                              hipStream_t stream) {
  (void)in_sizes; (void)n_in; (void)out_size; (void)ws_size;
  const float* x  = (const float*)d_in[0];
  const float* Wx = (const float*)d_in[1];
  const float* bx = (const float*)d_in[2];
  const float* Wh = (const float*)d_in[3];
  const float* Wp = (const float*)d_in[4];
  const float* bp = (const float*)d_in[5];
  float* out = (float*)d_out;
  unsigned char* ws = (unsigned char*)d_ws;

  // zero barrier counter + h0 double-buffer slot 0 (ws is poisoned 0xAA each launch)
  hipMemsetAsync(ws, 0, WS_HBUF + BDIM*HDIM*2, stream);

  hipLaunchKernelGGL(prep_kernel, dim3(1024), dim3(256), 0, stream, Wh, Wx, x, ws);

  hipFuncSetAttribute(reinterpret_cast<const void*>(&lstm_main),
                      hipFuncAttributeMaxDynamicSharedMemorySize, SMEM_BYTES);
  void* args[5];
  args[0] = (void*)&bx; args[1] = (void*)&Wp; args[2] = (void*)&bp;
  args[3] = (void*)&ws; args[4] = (void*)&out;
  hipLaunchCooperativeKernel(reinterpret_cast<const void*>(&lstm_main),
                             dim3(256), dim3(256), args, SMEM_BYTES, stream);
}

// Round 2
// 6315.669 us; speedup vs baseline: 1.0374x; 1.0374x over previous
//
#include <hip/hip_runtime.h>
#include <stdint.h>

// Problem dims
#define HDIM   1024
#define BDIM   128
#define TSTEPS 128
#define DDIM   256
#define ODIM   1024

// Workspace byte offsets
// control block: cnt[0]@0, cnt[1]@128, cnt2@256; flag[g][r]@512+(g*16+r)*128;
// flag2[r]@4608+r*128 (ends 6656)
#define WS_CNT   0
#define WS_FLAG  512
#define WS_FLAG2 4608
#define WS_HBUF  8192                                  // ushort [2][128][1024]
#define WS_HFIN  (WS_HBUF + 2*BDIM*HDIM*2)             // float  [128][1024]
#define WS_PBUF  (WS_HFIN + BDIM*HDIM*4)               // float  [128][1024]
#define WS_WHHI  (WS_PBUF + BDIM*ODIM*4)               // ushort [4096][1024]
#define WS_WHLO  (WS_WHHI + 4*HDIM*HDIM*2)             // ushort [4096][1024]
#define WS_WXHI  (WS_WHLO + 4*HDIM*HDIM*2)             // ushort [4096][256]
#define WS_XT    (WS_WXHI + 4*HDIM*DDIM*2)             // ushort [128][128][256]

// LDS layout (rows padded: 1288*2B=2576B, 1032*2B=2064B; both ≡16 mod 128 → conflict-free b128 rotation)
#define SMEM_WHI_ROW 1288   // 1024 Wh_hi + 256 Wx_hi + 8 pad
#define SMEM_WLO_ROW 1032   // 1024 Wh_lo + 8 pad
#define SMEM_BYTES   (32*SMEM_WHI_ROW*2 + 32*SMEM_WLO_ROW*2 + 64*33*4)  // 156,928 B

typedef __attribute__((ext_vector_type(8))) short frag8;
typedef __attribute__((ext_vector_type(4))) float f32x4;

__device__ __forceinline__ unsigned short f2bf(float f) {
  union { float f; unsigned u; } v; v.f = f;
  unsigned r = v.u + 0x7fffu + ((v.u >> 16) & 1u);   // RNE
  return (unsigned short)(r >> 16);
}
__device__ __forceinline__ float bf2f(unsigned short h) {
  union { unsigned u; float f; } v; v.u = ((unsigned)h) << 16;
  return v.f;
}
__device__ __forceinline__ float sigm(float x) { return 1.f / (1.f + __expf(-x)); }
__device__ __forceinline__ float tanh_f(float x) {
  x = fminf(fmaxf(x, -20.f), 20.f);
  float e = __expf(2.f * x);
  return (e - 1.f) / (e + 1.f);
}

// ---------------- prep: fp32 -> bf16 (hi/lo) reformat + x transpose ----------------
__global__ void prep_kernel(const float* __restrict__ Wh, const float* __restrict__ Wx,
                            const float* __restrict__ x, unsigned char* __restrict__ ws)
{
  unsigned short* whhi = (unsigned short*)(ws + WS_WHHI);
  unsigned short* whlo = (unsigned short*)(ws + WS_WHLO);
  unsigned short* wxhi = (unsigned short*)(ws + WS_WXHI);
  unsigned short* xt   = (unsigned short*)(ws + WS_XT);
  const int NWH = 4*HDIM*HDIM/4;       // 1,048,576 float4 items
  const int NWX = 4*HDIM*DDIM/4;       //   262,144
  const int NX  = BDIM*TSTEPS*DDIM/4;  // 1,048,576
  int stride = gridDim.x * blockDim.x;
  for (int i = blockIdx.x*blockDim.x + threadIdx.x; i < NWH+NWX+NX; i += stride) {
    if (i < NWH) {
      float4 w = ((const float4*)Wh)[i];
      ushort4 hi, lo;
      hi.x = f2bf(w.x); lo.x = f2bf(w.x - bf2f(hi.x));
      hi.y = f2bf(w.y); lo.y = f2bf(w.y - bf2f(hi.y));
      hi.z = f2bf(w.z); lo.z = f2bf(w.z - bf2f(hi.z));
      hi.w = f2bf(w.w); lo.w = f2bf(w.w - bf2f(hi.w));
      ((ushort4*)whhi)[i] = hi;
      ((ushort4*)whlo)[i] = lo;
    } else if (i < NWH + NWX) {
      int j = i - NWH;
      float4 w = ((const float4*)Wx)[j];
      ushort4 hi;
      hi.x = f2bf(w.x); hi.y = f2bf(w.y); hi.z = f2bf(w.z); hi.w = f2bf(w.w);
      ((ushort4*)wxhi)[j] = hi;
    } else {
      int j = i - NWH - NWX;           // x flat [b][t][dv], dv = float4 index
      int dv = j & 63;
      int t  = (j >> 6) & (TSTEPS - 1);
      int b  = j >> 13;
      float4 w = ((const float4*)x)[j];
      ushort4 hv;
      hv.x = f2bf(w.x); hv.y = f2bf(w.y); hv.z = f2bf(w.z); hv.w = f2bf(w.w);
      ((ushort4*)xt)[((size_t)t*BDIM + b)*64 + dv] = hv;   // xT[t][b][d]
    }
  }
}

// ---------------- persistent LSTM kernel (cooperative, 256 blocks x 256 thr) ----------------
// Block (mh = blockIdx&1, nsl = blockIdx>>1): batch rows [mh*64, +64), h-cols [nsl*8, +8)
// Barrier: 2 independent groups (by mh). Arrivals -> cnt[g] (add-only). Master block g
// (blockIdx==g) is the SOLE poller of cnt[g]; it fans the step out to 16 replica flag
// lines; waiters poll their own replica (≤8 pollers/line). Kills the R1 poll storm.
__global__ void __launch_bounds__(256, 1)
lstm_main(const float* __restrict__ bx, const float* __restrict__ Wp,
          const float* __restrict__ bp, unsigned char* __restrict__ ws,
          float* __restrict__ out)
{
  extern __shared__ unsigned char smem[];
  unsigned short* sWhi = (unsigned short*)smem;                            // [32][1288]
  unsigned short* sWlo = (unsigned short*)(smem + 32*SMEM_WHI_ROW*2);      // [32][1032]
  float*          sG   = (float*)(smem + 32*SMEM_WHI_ROW*2 + 32*SMEM_WLO_ROW*2); // [64][33]

  unsigned short* hbuf = (unsigned short*)(ws + WS_HBUF);
  float*          hfin = (float*)(ws + WS_HFIN);
  float*          pbuf = (float*)(ws + WS_PBUF);
  const unsigned short* whhi = (const unsigned short*)(ws + WS_WHHI);
  const unsigned short* whlo = (const unsigned short*)(ws + WS_WHLO);
  const unsigned short* wxhi = (const unsigned short*)(ws + WS_WXHI);
  const unsigned short* xt   = (const unsigned short*)(ws + WS_XT);

  const int tid  = threadIdx.x;
  const int lane = tid & 63;
  const int wv   = tid >> 6;      // wave 0..3 -> m-tile
  const int fr   = lane & 15;     // MFMA frag row (m for A, n for B)
  const int fg   = lane >> 4;     // k-group 0..3
  const int mh   = blockIdx.x & 1;
  const int nsl  = blockIdx.x >> 1;
  const int hc0  = nsl << 3;
  const int m0   = mh << 6;

  // barrier plumbing
  const int grp = mh;
  unsigned* cntg   = (unsigned*)(ws + WS_CNT + (size_t)grp*128);
  unsigned* cnt2   = (unsigned*)(ws + WS_CNT + 256);
  unsigned* flagg  = (unsigned*)(ws + WS_FLAG + (size_t)grp*2048);     // 16 replicas x 128B
  unsigned* myflag = flagg + ((unsigned)(nsl & 15))*32;
  unsigned* flag2  = (unsigned*)(ws + WS_FLAG2);
  const bool isMaster  = (blockIdx.x < 2);     // blockIdx==grp
  const bool isMaster0 = (blockIdx.x == 0);

  // ---- stage this block's weight slice into LDS (once) ----
  for (int lr = 0; lr < 32; ++lr) {
    int grow = (lr >> 3) * HDIM + hc0 + (lr & 7);   // gate*H + hcol
    ((ushort4*)(sWhi + lr*SMEM_WHI_ROW))[tid] =
        ((const ushort4*)(whhi + (size_t)grow*HDIM))[tid];
    ((ushort4*)(sWlo + lr*SMEM_WLO_ROW))[tid] =
        ((const ushort4*)(whlo + (size_t)grow*HDIM))[tid];
    if (tid < 64)
      ((ushort4*)(sWhi + lr*SMEM_WHI_ROW + 1024))[tid] =
          ((const ushort4*)(wxhi + (size_t)grow*DDIM))[tid];
  }
  __syncthreads();

  // update-phase mapping: items (uml0,uj) and (uml1,uj); biases invariant over t -> hoist
  const int uj   = tid & 7;
  const int uml0 = tid >> 3;
  const int uml1 = uml0 + 32;
  const float bg = bx[0*HDIM + hc0 + uj];
  const float bi = bx[1*HDIM + hc0 + uj];
  const float bf = bx[2*HDIM + hc0 + uj];
  const float bo = bx[3*HDIM + hc0 + uj];

  float c0 = 0.f, c1 = 0.f;
  const int arow = m0 + wv*16 + fr;   // global batch row for this lane's A-frags

  for (int t = 0; t < TSTEPS; ++t) {
    f32x4 acc0 = {0.f, 0.f, 0.f, 0.f};
    f32x4 acc1 = {0.f, 0.f, 0.f, 0.f};

    // ---- x-path (independent of h_t: overlaps the barrier wait) ----
    {
      const unsigned short* xrow = xt + ((size_t)t*BDIM + arow)*DDIM + fg*8;
      #pragma unroll
      for (int kc = 0; kc < 8; ++kc) {
        frag8 a  = *(const frag8*)(xrow + kc*32);
        frag8 b0 = *(const frag8*)(sWhi + fr*SMEM_WHI_ROW      + 1024 + kc*32 + fg*8);
        frag8 b1 = *(const frag8*)(sWhi + (16+fr)*SMEM_WHI_ROW + 1024 + kc*32 + fg*8);
        acc0 = __builtin_amdgcn_mfma_f32_16x16x32_bf16(a, b0, acc0, 0, 0, 0);
        acc1 = __builtin_amdgcn_mfma_f32_16x16x32_bf16(a, b1, acc1, 0, 0, 0);
      }
    }

    // ---- wait: h_t published for this group (flag >= t; t=0 trivially true) ----
    if (tid == 0 && !isMaster) {
      while (__hip_atomic_load(myflag, __ATOMIC_RELAXED, __HIP_MEMORY_SCOPE_AGENT) < (unsigned)t)
        __builtin_amdgcn_s_sleep(1);
      __threadfence();
    }
    __syncthreads();
    __threadfence();

    // ---- h-path: gates += h_t @ (Wh_hi + Wh_lo)^T ----
    {
      const unsigned short* hrow = hbuf + ((size_t)(t & 1)*BDIM + arow)*HDIM + fg*8;
      #pragma unroll 8
      for (int kc = 0; kc < 32; ++kc) {
        frag8 a   = *(const frag8*)(hrow + kc*32);
        frag8 bh0 = *(const frag8*)(sWhi + fr*SMEM_WHI_ROW      + kc*32 + fg*8);
        frag8 bh1 = *(const frag8*)(sWhi + (16+fr)*SMEM_WHI_ROW + kc*32 + fg*8);
        frag8 bl0 = *(const frag8*)(sWlo + fr*SMEM_WLO_ROW      + kc*32 + fg*8);
        frag8 bl1 = *(const frag8*)(sWlo + (16+fr)*SMEM_WLO_ROW + kc*32 + fg*8);
        acc0 = __builtin_amdgcn_mfma_f32_16x16x32_bf16(a, bh0, acc0, 0, 0, 0);
        acc1 = __builtin_amdgcn_mfma_f32_16x16x32_bf16(a, bh1, acc1, 0, 0, 0);
        acc0 = __builtin_amdgcn_mfma_f32_16x16x32_bf16(a, bl0, acc0, 0, 0, 0);
        acc1 = __builtin_amdgcn_mfma_f32_16x16x32_bf16(a, bl1, acc1, 0, 0, 0);
      }
    }

    // ---- scatter accs to LDS (C/D layout: col=lane&15, row=(lane>>4)*4+reg) ----
    {
      int mb = wv*16 + fg*4;
      #pragma unroll
      for (int r = 0; r < 4; ++r) {
        sG[(mb + r)*33 + fr]      = acc0[r];
        sG[(mb + r)*33 + 16 + fr] = acc1[r];
      }
    }
    __syncthreads();

    // ---- gate nonlinearities + state update (c stays in registers) ----
    {
      float gg0 = sG[uml0*33 + uj]      + bg;
      float gi0 = sG[uml0*33 + 8 + uj]  + bi;
      float gf0 = sG[uml0*33 + 16 + uj] + bf;
      float go0 = sG[uml0*33 + 24 + uj] + bo;
      float gg1 = sG[uml1*33 + uj]      + bg;
      float gi1 = sG[uml1*33 + 8 + uj]  + bi;
      float gf1 = sG[uml1*33 + 16 + uj] + bf;
      float go1 = sG[uml1*33 + 24 + uj] + bo;

      c0 = tanh_f(gg0)*sigm(gi0) + c0*sigm(gf0);
      c1 = tanh_f(gg1)*sigm(gi1) + c1*sigm(gf1);
      float h0 = tanh_f(c0)*sigm(go0);
      float h1 = tanh_f(c1)*sigm(go1);

      unsigned short* hw = hbuf + (size_t)((t + 1) & 1)*BDIM*HDIM;
      hw[(size_t)(m0 + uml0)*HDIM + hc0 + uj] = f2bf(h0);
      hw[(size_t)(m0 + uml1)*HDIM + hc0 + uj] = f2bf(h1);
      if (t == TSTEPS - 1) {
        hfin[(size_t)(m0 + uml0)*HDIM + hc0 + uj] = h0;
        hfin[(size_t)(m0 + uml1)*HDIM + hc0 + uj] = h1;
      }
    }

    // ---- arrive (release) ----
    __threadfence();
    __syncthreads();
    if (tid == 0) {
      __hip_atomic_fetch_add(cntg, 1u, __ATOMIC_RELAXED, __HIP_MEMORY_SCOPE_AGENT);
      if (isMaster) {
        unsigned tgt = 128u * (unsigned)(t + 1);
        while (__hip_atomic_load(cntg, __ATOMIC_RELAXED, __HIP_MEMORY_SCOPE_AGENT) < tgt)
          __builtin_amdgcn_s_sleep(1);
        __threadfence();
        #pragma unroll
        for (int r = 0; r < 16; ++r)
          __hip_atomic_store(flagg + r*32, (unsigned)(t + 1),
                             __ATOMIC_RELAXED, __HIP_MEMORY_SCOPE_AGENT);
      }
    }
  }

  // ---- wait: own group finished all steps (hfin complete for our rows) ----
  if (tid == 0 && !isMaster) {
    while (__hip_atomic_load(myflag, __ATOMIC_RELAXED, __HIP_MEMORY_SCOPE_AGENT) < (unsigned)TSTEPS)
      __builtin_amdgcn_s_sleep(1);
    __threadfence();
  }
  __syncthreads();
  __threadfence();

  // ---- projection: p = h_last @ Wp^T + bp (fp32 vector; block covers [m0,+64) x [hc0,+8)) ----
  {
    #pragma unroll
    for (int it = 0; it < 2; ++it) {
      int ml = (it == 0) ? uml0 : uml1;
      int m = m0 + ml, n = hc0 + uj;
      const float4* hr = (const float4*)(hfin + (size_t)m*HDIM);
      const float4* wr = (const float4*)(Wp + (size_t)n*HDIM);
      float s = 0.f;
      #pragma unroll 4
      for (int k = 0; k < HDIM/4; ++k) {
        float4 a = hr[k], b = wr[k];
        s += a.x*b.x + a.y*b.y + a.z*b.z + a.w*b.w;
      }
      pbuf[(size_t)m*ODIM + n] = s + bp[n];
    }
  }

  // ---- one-shot full-grid barrier (pbuf complete), then softmax on blocks < 128 ----
  __threadfence();
  __syncthreads();
  if (tid == 0) {
    __hip_atomic_fetch_add(cnt2, 1u, __ATOMIC_RELAXED, __HIP_MEMORY_SCOPE_AGENT);
    if (isMaster0) {
      while (__hip_atomic_load(cnt2, __ATOMIC_RELAXED, __HIP_MEMORY_SCOPE_AGENT) < 256u)
        __builtin_amdgcn_s_sleep(1);
      __threadfence();
      #pragma unroll
      for (int r = 0; r < 16; ++r)
        __hip_atomic_store(flag2 + r*32, 1u, __ATOMIC_RELAXED, __HIP_MEMORY_SCOPE_AGENT);
    }
  }

  if (blockIdx.x >= BDIM) return;

  if (tid == 0 && !isMaster0) {
    while (__hip_atomic_load(flag2 + (blockIdx.x & 15)*32,
                             __ATOMIC_RELAXED, __HIP_MEMORY_SCOPE_AGENT) < 1u)
      __builtin_amdgcn_s_sleep(1);
    __threadfence();
  }
  __syncthreads();
  __threadfence();

  // ---- softmax: one block per batch row ----
  {
    int b = blockIdx.x;
    float4 v = ((const float4*)(pbuf + (size_t)b*ODIM))[tid];
    float mx = fmaxf(fmaxf(v.x, v.y), fmaxf(v.z, v.w));
    #pragma unroll
    for (int off = 32; off > 0; off >>= 1)
      mx = fmaxf(mx, __shfl_xor(mx, off, 64));
    if (lane == 0) sG[wv] = mx;
    __syncthreads();
    mx = fmaxf(fmaxf(sG[0], sG[1]), fmaxf(sG[2], sG[3]));
    float e0 = __expf(v.x - mx), e1 = __expf(v.y - mx),
          e2 = __expf(v.z - mx), e3 = __expf(v.w - mx);
    float s = e0 + e1 + e2 + e3;
    #pragma unroll
    for (int off = 32; off > 0; off >>= 1)
      s += __shfl_xor(s, off, 64);
    if (lane == 0) sG[8 + wv] = s;
    __syncthreads();
    s = sG[8] + sG[9] + sG[10] + sG[11];
    float inv = 1.f / s;
    float4 o; o.x = e0*inv; o.y = e1*inv; o.z = e2*inv; o.w = e3*inv;
    ((float4*)(out + (size_t)b*ODIM))[tid] = o;
  }
}

// ---------------- host launch ----------------
extern "C" void kernel_launch(void* const* d_in, const int* in_sizes, int n_in,
                              void* d_out, int out_size, void* d_ws, size_t ws_size,
                              hipStream_t stream) {
  (void)in_sizes; (void)n_in; (void)out_size; (void)ws_size;
  const float* x  = (const float*)d_in[0];
  const float* Wx = (const float*)d_in[1];
  const float* bx = (const float*)d_in[2];
  const float* Wh = (const float*)d_in[3];
  const float* Wp = (const float*)d_in[4];
  const float* bp = (const float*)d_in[5];
  float* out = (float*)d_out;
  unsigned char* ws = (unsigned char*)d_ws;

  // zero control block (counters + flags) + h0 double-buffer slot 0
  hipMemsetAsync(ws, 0, WS_HBUF + BDIM*HDIM*2, stream);

  hipLaunchKernelGGL(prep_kernel, dim3(1024), dim3(256), 0, stream, Wh, Wx, x, ws);

  hipFuncSetAttribute(reinterpret_cast<const void*>(&lstm_main),
                      hipFuncAttributeMaxDynamicSharedMemorySize, SMEM_BYTES);
  void* args[5];
  args[0] = (void*)&bx; args[1] = (void*)&Wp; args[2] = (void*)&bp;
  args[3] = (void*)&ws; args[4] = (void*)&out;
  hipLaunchCooperativeKernel(reinterpret_cast<const void*>(&lstm_main),
                             dim3(256), dim3(256), args, SMEM_BYTES, stream);
}

// Round 3
// 1557.807 us; speedup vs baseline: 4.2058x; 4.0542x over previous
//
#include <hip/hip_runtime.h>
#include <stdint.h>

// Problem dims
#define HDIM   1024
#define BDIM   128
#define TSTEPS 128
#define DDIM   256
#define ODIM   1024

// Workspace byte offsets
// control block: cnt[0]@0, cnt[1]@128, cnt2@256; flag[g][r]@512+(g*16+r)*128;
// flag2[r]@4608+r*128 (ends 6656)
#define WS_CNT   0
#define WS_FLAG  512
#define WS_FLAG2 4608
#define WS_HBUF  8192                                  // ushort [2][128][1024]
#define WS_HFIN  (WS_HBUF + 2*BDIM*HDIM*2)             // float  [128][1024]
#define WS_PBUF  (WS_HFIN + BDIM*HDIM*4)               // float  [128][1024]
#define WS_WHHI  (WS_PBUF + BDIM*ODIM*4)               // ushort [4096][1024]
#define WS_WHLO  (WS_WHHI + 4*HDIM*HDIM*2)             // ushort [4096][1024]
#define WS_WXHI  (WS_WHLO + 4*HDIM*HDIM*2)             // ushort [4096][256]
#define WS_XT    (WS_WXHI + 4*HDIM*DDIM*2)             // ushort [128][128][256]

// LDS layout (rows padded: 1288*2B=2576B, 1032*2B=2064B; conflict-free b128 rotation)
#define SMEM_WHI_ROW 1288   // 1024 Wh_hi + 256 Wx_hi + 8 pad
#define SMEM_WLO_ROW 1032   // 1024 Wh_lo + 8 pad
#define SMEM_BYTES   (32*SMEM_WHI_ROW*2 + 32*SMEM_WLO_ROW*2 + 64*33*4)  // 156,928 B

typedef __attribute__((ext_vector_type(8))) short frag8;
typedef __attribute__((ext_vector_type(4))) float f32x4;

__device__ __forceinline__ unsigned short f2bf(float f) {
  union { float f; unsigned u; } v; v.f = f;
  unsigned r = v.u + 0x7fffu + ((v.u >> 16) & 1u);   // RNE
  return (unsigned short)(r >> 16);
}
__device__ __forceinline__ float bf2f(unsigned short h) {
  union { unsigned u; float f; } v; v.u = ((unsigned)h) << 16;
  return v.f;
}
__device__ __forceinline__ float sigm(float x) { return 1.f / (1.f + __expf(-x)); }
__device__ __forceinline__ float tanh_f(float x) {
  x = fminf(fmaxf(x, -20.f), 20.f);
  float e = __expf(2.f * x);
  return (e - 1.f) / (e + 1.f);
}

// Coherence idiom (gfx950, non-coherent per-XCD L2):
//  - producers store cross-block data with relaxed AGENT atomic stores (sc0 sc1:
//    write-through to LLC; L2 never holds dirty lines -> no buffer_wbl2 anywhere)
//  - release ordering: __syncthreads() drains vmcnt(0) before tid0's arrive-add
//  - consumers: relaxed poll, then ONE __builtin_amdgcn_fence(ACQUIRE,"agent")
//    (single buffer_inv sc1), after which bulk reads are normal cached loads.
__device__ __forceinline__ void st_agent_u16(unsigned short* p, unsigned short v) {
  __hip_atomic_store(p, v, __ATOMIC_RELAXED, __HIP_MEMORY_SCOPE_AGENT);
}
__device__ __forceinline__ void st_agent_f32(float* p, float v) {
  __hip_atomic_store(p, v, __ATOMIC_RELAXED, __HIP_MEMORY_SCOPE_AGENT);
}

// ---------------- prep: fp32 -> bf16 (hi/lo) reformat + x transpose ----------------
__global__ void prep_kernel(const float* __restrict__ Wh, const float* __restrict__ Wx,
                            const float* __restrict__ x, unsigned char* __restrict__ ws)
{
  unsigned short* whhi = (unsigned short*)(ws + WS_WHHI);
  unsigned short* whlo = (unsigned short*)(ws + WS_WHLO);
  unsigned short* wxhi = (unsigned short*)(ws + WS_WXHI);
  unsigned short* xt   = (unsigned short*)(ws + WS_XT);
  const int NWH = 4*HDIM*HDIM/4;       // 1,048,576 float4 items
  const int NWX = 4*HDIM*DDIM/4;       //   262,144
  const int NX  = BDIM*TSTEPS*DDIM/4;  // 1,048,576
  int stride = gridDim.x * blockDim.x;
  for (int i = blockIdx.x*blockDim.x + threadIdx.x; i < NWH+NWX+NX; i += stride) {
    if (i < NWH) {
      float4 w = ((const float4*)Wh)[i];
      ushort4 hi, lo;
      hi.x = f2bf(w.x); lo.x = f2bf(w.x - bf2f(hi.x));
      hi.y = f2bf(w.y); lo.y = f2bf(w.y - bf2f(hi.y));
      hi.z = f2bf(w.z); lo.z = f2bf(w.z - bf2f(hi.z));
      hi.w = f2bf(w.w); lo.w = f2bf(w.w - bf2f(hi.w));
      ((ushort4*)whhi)[i] = hi;
      ((ushort4*)whlo)[i] = lo;
    } else if (i < NWH + NWX) {
      int j = i - NWH;
      float4 w = ((const float4*)Wx)[j];
      ushort4 hi;
      hi.x = f2bf(w.x); hi.y = f2bf(w.y); hi.z = f2bf(w.z); hi.w = f2bf(w.w);
      ((ushort4*)wxhi)[j] = hi;
    } else {
      int j = i - NWH - NWX;           // x flat [b][t][dv], dv = float4 index
      int dv = j & 63;
      int t  = (j >> 6) & (TSTEPS - 1);
      int b  = j >> 13;
      float4 w = ((const float4*)x)[j];
      ushort4 hv;
      hv.x = f2bf(w.x); hv.y = f2bf(w.y); hv.z = f2bf(w.z); hv.w = f2bf(w.w);
      ((ushort4*)xt)[((size_t)t*BDIM + b)*64 + dv] = hv;   // xT[t][b][d]
    }
  }
}

// ---------------- persistent LSTM kernel (cooperative, 256 blocks x 256 thr) ----------------
// Block (mh = blockIdx&1, nsl = blockIdx>>1): batch rows [mh*64, +64), h-cols [nsl*8, +8)
// Barrier: 2 independent groups (by mh); add-only arrivals, master fans out to 16 replica
// flag lines. NO __threadfence anywhere (see coherence idiom above).
__global__ void __launch_bounds__(256, 1)
lstm_main(const float* __restrict__ bx, const float* __restrict__ Wp,
          const float* __restrict__ bp, unsigned char* __restrict__ ws,
          float* __restrict__ out)
{
  extern __shared__ unsigned char smem[];
  unsigned short* sWhi = (unsigned short*)smem;                            // [32][1288]
  unsigned short* sWlo = (unsigned short*)(smem + 32*SMEM_WHI_ROW*2);      // [32][1032]
  float*          sG   = (float*)(smem + 32*SMEM_WHI_ROW*2 + 32*SMEM_WLO_ROW*2); // [64][33]

  unsigned short* hbuf = (unsigned short*)(ws + WS_HBUF);
  float*          hfin = (float*)(ws + WS_HFIN);
  float*          pbuf = (float*)(ws + WS_PBUF);
  const unsigned short* whhi = (const unsigned short*)(ws + WS_WHHI);
  const unsigned short* whlo = (const unsigned short*)(ws + WS_WHLO);
  const unsigned short* wxhi = (const unsigned short*)(ws + WS_WXHI);
  const unsigned short* xt   = (const unsigned short*)(ws + WS_XT);

  const int tid  = threadIdx.x;
  const int lane = tid & 63;
  const int wv   = tid >> 6;      // wave 0..3 -> m-tile
  const int fr   = lane & 15;     // MFMA frag row (m for A, n for B)
  const int fg   = lane >> 4;     // k-group 0..3
  const int mh   = blockIdx.x & 1;
  const int nsl  = blockIdx.x >> 1;
  const int hc0  = nsl << 3;
  const int m0   = mh << 6;

  // barrier plumbing
  const int grp = mh;
  unsigned* cntg   = (unsigned*)(ws + WS_CNT + (size_t)grp*128);
  unsigned* cnt2   = (unsigned*)(ws + WS_CNT + 256);
  unsigned* flagg  = (unsigned*)(ws + WS_FLAG + (size_t)grp*2048);     // 16 replicas x 128B
  unsigned* myflag = flagg + ((unsigned)(nsl & 15))*32;
  unsigned* flag2  = (unsigned*)(ws + WS_FLAG2);
  const bool isMaster  = (blockIdx.x < 2);     // blockIdx==grp
  const bool isMaster0 = (blockIdx.x == 0);

  // ---- stage this block's weight slice into LDS (once) ----
  for (int lr = 0; lr < 32; ++lr) {
    int grow = (lr >> 3) * HDIM + hc0 + (lr & 7);   // gate*H + hcol
    ((ushort4*)(sWhi + lr*SMEM_WHI_ROW))[tid] =
        ((const ushort4*)(whhi + (size_t)grow*HDIM))[tid];
    ((ushort4*)(sWlo + lr*SMEM_WLO_ROW))[tid] =
        ((const ushort4*)(whlo + (size_t)grow*HDIM))[tid];
    if (tid < 64)
      ((ushort4*)(sWhi + lr*SMEM_WHI_ROW + 1024))[tid] =
          ((const ushort4*)(wxhi + (size_t)grow*DDIM))[tid];
  }
  __syncthreads();

  // update-phase mapping: items (uml0,uj) and (uml1,uj); biases invariant over t -> hoist
  const int uj   = tid & 7;
  const int uml0 = tid >> 3;
  const int uml1 = uml0 + 32;
  const float bg = bx[0*HDIM + hc0 + uj];
  const float bi = bx[1*HDIM + hc0 + uj];
  const float bf = bx[2*HDIM + hc0 + uj];
  const float bo = bx[3*HDIM + hc0 + uj];

  float c0 = 0.f, c1 = 0.f;
  const int arow = m0 + wv*16 + fr;   // global batch row for this lane's A-frags

  for (int t = 0; t < TSTEPS; ++t) {
    f32x4 acc0 = {0.f, 0.f, 0.f, 0.f};
    f32x4 acc1 = {0.f, 0.f, 0.f, 0.f};

    // ---- x-path (independent of h_t: overlaps the barrier wait) ----
    {
      const unsigned short* xrow = xt + ((size_t)t*BDIM + arow)*DDIM + fg*8;
      #pragma unroll
      for (int kc = 0; kc < 8; ++kc) {
        frag8 a  = *(const frag8*)(xrow + kc*32);
        frag8 b0 = *(const frag8*)(sWhi + fr*SMEM_WHI_ROW      + 1024 + kc*32 + fg*8);
        frag8 b1 = *(const frag8*)(sWhi + (16+fr)*SMEM_WHI_ROW + 1024 + kc*32 + fg*8);
        acc0 = __builtin_amdgcn_mfma_f32_16x16x32_bf16(a, b0, acc0, 0, 0, 0);
        acc1 = __builtin_amdgcn_mfma_f32_16x16x32_bf16(a, b1, acc1, 0, 0, 0);
      }
    }

    // ---- wait: h_t published for this group (flag >= t; t=0 trivially true) ----
    if (tid == 0 && !isMaster) {
      while (__hip_atomic_load(myflag, __ATOMIC_RELAXED, __HIP_MEMORY_SCOPE_AGENT) < (unsigned)t)
        __builtin_amdgcn_s_sleep(1);
      __builtin_amdgcn_fence(__ATOMIC_ACQUIRE, "agent");   // one buffer_inv; no wbl2
    }
    __syncthreads();

    // ---- h-path: gates += h_t @ (Wh_hi + Wh_lo)^T (normal cached loads, post-inv) ----
    {
      const unsigned short* hrow = hbuf + ((size_t)(t & 1)*BDIM + arow)*HDIM + fg*8;
      #pragma unroll 8
      for (int kc = 0; kc < 32; ++kc) {
        frag8 a   = *(const frag8*)(hrow + kc*32);
        frag8 bh0 = *(const frag8*)(sWhi + fr*SMEM_WHI_ROW      + kc*32 + fg*8);
        frag8 bh1 = *(const frag8*)(sWhi + (16+fr)*SMEM_WHI_ROW + kc*32 + fg*8);
        frag8 bl0 = *(const frag8*)(sWlo + fr*SMEM_WLO_ROW      + kc*32 + fg*8);
        frag8 bl1 = *(const frag8*)(sWlo + (16+fr)*SMEM_WLO_ROW + kc*32 + fg*8);
        acc0 = __builtin_amdgcn_mfma_f32_16x16x32_bf16(a, bh0, acc0, 0, 0, 0);
        acc1 = __builtin_amdgcn_mfma_f32_16x16x32_bf16(a, bh1, acc1, 0, 0, 0);
        acc0 = __builtin_amdgcn_mfma_f32_16x16x32_bf16(a, bl0, acc0, 0, 0, 0);
        acc1 = __builtin_amdgcn_mfma_f32_16x16x32_bf16(a, bl1, acc1, 0, 0, 0);
      }
    }

    // ---- scatter accs to LDS (C/D layout: col=lane&15, row=(lane>>4)*4+reg) ----
    {
      int mb = wv*16 + fg*4;
      #pragma unroll
      for (int r = 0; r < 4; ++r) {
        sG[(mb + r)*33 + fr]      = acc0[r];
        sG[(mb + r)*33 + 16 + fr] = acc1[r];
      }
    }
    __syncthreads();

    // ---- gate nonlinearities + state update (c stays in registers) ----
    {
      float gg0 = sG[uml0*33 + uj]      + bg;
      float gi0 = sG[uml0*33 + 8 + uj]  + bi;
      float gf0 = sG[uml0*33 + 16 + uj] + bf;
      float go0 = sG[uml0*33 + 24 + uj] + bo;
      float gg1 = sG[uml1*33 + uj]      + bg;
      float gi1 = sG[uml1*33 + 8 + uj]  + bi;
      float gf1 = sG[uml1*33 + 16 + uj] + bf;
      float go1 = sG[uml1*33 + 24 + uj] + bo;

      c0 = tanh_f(gg0)*sigm(gi0) + c0*sigm(gf0);
      c1 = tanh_f(gg1)*sigm(gi1) + c1*sigm(gf1);
      float h0 = tanh_f(c0)*sigm(go0);
      float h1 = tanh_f(c1)*sigm(go1);

      // write-through (sc1) stores: cross-XCD visible at LLC, nothing dirty in L2
      unsigned short* hw = hbuf + (size_t)((t + 1) & 1)*BDIM*HDIM;
      st_agent_u16(hw + (size_t)(m0 + uml0)*HDIM + hc0 + uj, f2bf(h0));
      st_agent_u16(hw + (size_t)(m0 + uml1)*HDIM + hc0 + uj, f2bf(h1));
      if (t == TSTEPS - 1) {
        st_agent_f32(hfin + (size_t)(m0 + uml0)*HDIM + hc0 + uj, h0);
        st_agent_f32(hfin + (size_t)(m0 + uml1)*HDIM + hc0 + uj, h1);
      }
    }

    // ---- arrive: syncthreads drains vmcnt(0) (release), then add ----
    __syncthreads();
    if (tid == 0) {
      __hip_atomic_fetch_add(cntg, 1u, __ATOMIC_RELAXED, __HIP_MEMORY_SCOPE_AGENT);
      if (isMaster) {
        unsigned tgt = 128u * (unsigned)(t + 1);
        while (__hip_atomic_load(cntg, __ATOMIC_RELAXED, __HIP_MEMORY_SCOPE_AGENT) < tgt)
          __builtin_amdgcn_s_sleep(1);
        __builtin_amdgcn_fence(__ATOMIC_ACQUIRE, "agent");
        #pragma unroll
        for (int r = 0; r < 16; ++r)
          __hip_atomic_store(flagg + r*32, (unsigned)(t + 1),
                             __ATOMIC_RELAXED, __HIP_MEMORY_SCOPE_AGENT);
      }
    }
  }

  // ---- wait: own group finished all steps (hfin complete for our rows) ----
  if (tid == 0) {
    if (!isMaster) {
      while (__hip_atomic_load(myflag, __ATOMIC_RELAXED, __HIP_MEMORY_SCOPE_AGENT) < (unsigned)TSTEPS)
        __builtin_amdgcn_s_sleep(1);
    }
    __builtin_amdgcn_fence(__ATOMIC_ACQUIRE, "agent");
  }
  __syncthreads();

  // ---- projection: p = h_last @ Wp^T + bp (fp32 vector; block covers [m0,+64) x [hc0,+8)) ----
  {
    #pragma unroll
    for (int it = 0; it < 2; ++it) {
      int ml = (it == 0) ? uml0 : uml1;
      int m = m0 + ml, n = hc0 + uj;
      const float4* hr = (const float4*)(hfin + (size_t)m*HDIM);
      const float4* wr = (const float4*)(Wp + (size_t)n*HDIM);
      float s = 0.f;
      #pragma unroll 4
      for (int k = 0; k < HDIM/4; ++k) {
        float4 a = hr[k], b = wr[k];
        s += a.x*b.x + a.y*b.y + a.z*b.z + a.w*b.w;
      }
      st_agent_f32(&pbuf[(size_t)m*ODIM + n], s + bp[n]);
    }
  }

  // ---- one-shot full-grid barrier (pbuf complete), then softmax on blocks < 128 ----
  __syncthreads();
  if (tid == 0) {
    __hip_atomic_fetch_add(cnt2, 1u, __ATOMIC_RELAXED, __HIP_MEMORY_SCOPE_AGENT);
    if (isMaster0) {
      while (__hip_atomic_load(cnt2, __ATOMIC_RELAXED, __HIP_MEMORY_SCOPE_AGENT) < 256u)
        __builtin_amdgcn_s_sleep(1);
      __builtin_amdgcn_fence(__ATOMIC_ACQUIRE, "agent");
      #pragma unroll
      for (int r = 0; r < 16; ++r)
        __hip_atomic_store(flag2 + r*32, 1u, __ATOMIC_RELAXED, __HIP_MEMORY_SCOPE_AGENT);
    }
  }

  if (blockIdx.x >= BDIM) return;

  if (tid == 0) {
    if (!isMaster0) {
      while (__hip_atomic_load(flag2 + (blockIdx.x & 15)*32,
                               __ATOMIC_RELAXED, __HIP_MEMORY_SCOPE_AGENT) < 1u)
        __builtin_amdgcn_s_sleep(1);
    }
    __builtin_amdgcn_fence(__ATOMIC_ACQUIRE, "agent");  // inv: kills any stale pbuf lines
  }
  __syncthreads();

  // ---- softmax: one block per batch row ----
  {
    int b = blockIdx.x;
    float4 v = ((const float4*)(pbuf + (size_t)b*ODIM))[tid];
    float mx = fmaxf(fmaxf(v.x, v.y), fmaxf(v.z, v.w));
    #pragma unroll
    for (int off = 32; off > 0; off >>= 1)
      mx = fmaxf(mx, __shfl_xor(mx, off, 64));
    if (lane == 0) sG[wv] = mx;
    __syncthreads();
    mx = fmaxf(fmaxf(sG[0], sG[1]), fmaxf(sG[2], sG[3]));
    float e0 = __expf(v.x - mx), e1 = __expf(v.y - mx),
          e2 = __expf(v.z - mx), e3 = __expf(v.w - mx);
    float s = e0 + e1 + e2 + e3;
    #pragma unroll
    for (int off = 32; off > 0; off >>= 1)
      s += __shfl_xor(s, off, 64);
    if (lane == 0) sG[8 + wv] = s;
    __syncthreads();
    s = sG[8] + sG[9] + sG[10] + sG[11];
    float inv = 1.f / s;
    float4 o; o.x = e0*inv; o.y = e1*inv; o.z = e2*inv; o.w = e3*inv;
    ((float4*)(out + (size_t)b*ODIM))[tid] = o;
  }
}

// ---------------- host launch ----------------
extern "C" void kernel_launch(void* const* d_in, const int* in_sizes, int n_in,
                              void* d_out, int out_size, void* d_ws, size_t ws_size,
                              hipStream_t stream) {
  (void)in_sizes; (void)n_in; (void)out_size; (void)ws_size;
  const float* x  = (const float*)d_in[0];
  const float* Wx = (const float*)d_in[1];
  const float* bx = (const float*)d_in[2];
  const float* Wh = (const float*)d_in[3];
  const float* Wp = (const float*)d_in[4];
  const float* bp = (const float*)d_in[5];
  float* out = (float*)d_out;
  unsigned char* ws = (unsigned char*)d_ws;

  // zero control block (counters + flags) + h0 double-buffer slot 0
  hipMemsetAsync(ws, 0, WS_HBUF + BDIM*HDIM*2, stream);

  hipLaunchKernelGGL(prep_kernel, dim3(1024), dim3(256), 0, stream, Wh, Wx, x, ws);

  hipFuncSetAttribute(reinterpret_cast<const void*>(&lstm_main),
                      hipFuncAttributeMaxDynamicSharedMemorySize, SMEM_BYTES);
  void* args[5];
  args[0] = (void*)&bx; args[1] = (void*)&Wp; args[2] = (void*)&bp;
  args[3] = (void*)&ws; args[4] = (void*)&out;
  hipLaunchCooperativeKernel(reinterpret_cast<const void*>(&lstm_main),
                             dim3(256), dim3(256), args, SMEM_BYTES, stream);
}